// Round 3
// baseline (848.095 us; speedup 1.0000x reference)
//
#include <hip/hip_runtime.h>
#include <hip/hip_cooperative_groups.h>
#include <math.h>

namespace cg = cooperative_groups;

#define NN 4096
#define DD 256
#define EPSV 1e-4f
#define STABV 1e-8f
#define AVAL (1.0f / 4096.0f)
#define BVAL (1.0f / 4096.0f)
#define MAX_IT 2000

typedef __attribute__((ext_vector_type(4))) float f32x4;
typedef __attribute__((ext_vector_type(8))) short bf16x8;

__device__ inline unsigned short f2bf(float f) {   // RNE f32->bf16
    unsigned u = __float_as_uint(f);
    return (unsigned short)((u + 0x7fffu + ((u >> 16) & 1u)) >> 16);
}
__device__ inline float bflo(unsigned w) { return __uint_as_float(w << 16); }
__device__ inline float bfhi(unsigned w) { return __uint_as_float(w & 0xffff0000u); }

// ---------------- init ----------------
__global__ void sk_init_kernel(float* sumC, unsigned* flags, float* out) {
    if (threadIdx.x == 0) {
        sumC[0] = 0.0f;
        flags[0] = 0u;
        flags[1] = 0u;
        out[0] = 0.0f;
    }
}

// ---------------- convert f32 -> bf16 + row norms (f32) ----------------
__global__ __launch_bounds__(256) void sk_conv_kernel(const float* __restrict__ x,
                                                      const float* __restrict__ y,
                                                      unsigned short* __restrict__ xb,
                                                      unsigned short* __restrict__ yb,
                                                      float* __restrict__ x2,
                                                      float* __restrict__ y2) {
    int w = blockIdx.x * 4 + (threadIdx.x >> 6);   // row id 0..8191
    int lane = threadIdx.x & 63;
    const float* src = (w < NN) ? (x + (size_t)w * DD) : (y + (size_t)(w - NN) * DD);
    unsigned short* dst = (w < NN) ? (xb + (size_t)w * DD) : (yb + (size_t)(w - NN) * DD);
    float4 v = *(const float4*)(src + lane * 4);
    float s = v.x * v.x + v.y * v.y + v.z * v.z + v.w * v.w;
    ushort4 p;
    p.x = f2bf(v.x); p.y = f2bf(v.y); p.z = f2bf(v.z); p.w = f2bf(v.w);
    *(ushort4*)(dst + lane * 4) = p;
#pragma unroll
    for (int off = 32; off > 0; off >>= 1) s += __shfl_down(s, off, 64);
    if (lane == 0) {
        if (w < NN) x2[w] = s; else y2[w - NN] = s;
    }
}

// ---------------- MFMA GEMM: Cb = bf16( sqrt(max(x2_i + y2_j - 2 x.y, 0)) ), sum(C) ----------------
__global__ __launch_bounds__(256) void sk_gemm_kernel(const unsigned short* __restrict__ xb,
                                                      const unsigned short* __restrict__ yb,
                                                      const float* __restrict__ x2,
                                                      const float* __restrict__ y2,
                                                      unsigned short* __restrict__ Cb,
                                                      float* __restrict__ sumC) {
    __shared__ float red[256];
    const int tid = threadIdx.x;
    const int wid = tid >> 6, lane = tid & 63;
    const int wy = wid >> 1, wx = wid & 1;
    const int rb = blockIdx.y * 128 + wy * 64;
    const int cb = blockIdx.x * 128 + wx * 64;
    const int lr = lane & 15;          // row/col within 16x16 tile
    const int lk = (lane >> 4) * 8;    // k offset of this lane's 8 elements

    f32x4 acc[4][4];
    const f32x4 z4 = {0.0f, 0.0f, 0.0f, 0.0f};
#pragma unroll
    for (int a = 0; a < 4; ++a)
#pragma unroll
        for (int b = 0; b < 4; ++b) acc[a][b] = z4;

#pragma unroll
    for (int k0 = 0; k0 < DD; k0 += 32) {
        bf16x8 af[4], bfr[4];
#pragma unroll
        for (int t = 0; t < 4; ++t)
            af[t] = *(const bf16x8*)(xb + (size_t)(rb + t * 16 + lr) * DD + k0 + lk);
#pragma unroll
        for (int t = 0; t < 4; ++t)
            bfr[t] = *(const bf16x8*)(yb + (size_t)(cb + t * 16 + lr) * DD + k0 + lk);
#pragma unroll
        for (int ty = 0; ty < 4; ++ty)
#pragma unroll
            for (int tx = 0; tx < 4; ++tx)
                acc[ty][tx] = __builtin_amdgcn_mfma_f32_16x16x32_bf16(af[ty], bfr[tx], acc[ty][tx], 0, 0, 0);
    }

    float lsum = 0.0f;
#pragma unroll
    for (int ty = 0; ty < 4; ++ty) {
        float x2r[4];
#pragma unroll
        for (int r = 0; r < 4; ++r)
            x2r[r] = x2[rb + ty * 16 + (lane >> 4) * 4 + r];
#pragma unroll
        for (int tx = 0; tx < 4; ++tx) {
            int col = cb + tx * 16 + lr;
            float y2c = y2[col];
#pragma unroll
            for (int r = 0; r < 4; ++r) {
                int row = rb + ty * 16 + (lane >> 4) * 4 + r;
                float sq = x2r[r] + y2c - 2.0f * acc[ty][tx][r];
                float c = sqrtf(fmaxf(sq, 0.0f));
                lsum += c;
                Cb[(size_t)row * NN + col] = f2bf(c);
            }
        }
    }
    red[tid] = lsum;
    __syncthreads();
    for (int off = 128; off > 0; off >>= 1) {
        if (tid < off) red[tid] += red[tid + off];
        __syncthreads();
    }
    if (tid == 0) atomicAdd(sumC, red[0]);
}

// ---------------- cooperative Sinkhorn loop + cost + outputs ----------------
// Grid-size-generic: works for gridDim.x in {512, 1024} (256 threads/block).
// LDS kept at 1 KB so cooperative occupancy is not LDS-limited.
__global__ __launch_bounds__(256, 4) void sk_coop_kernel(const unsigned short* __restrict__ Cb,
                                                         float* __restrict__ u,
                                                         float* __restrict__ v,
                                                         float* __restrict__ s,
                                                         const float* __restrict__ sumC,
                                                         unsigned* __restrict__ flags,
                                                         float* __restrict__ out) {
    cg::grid_group grid = cg::this_grid();
    __shared__ float red[256];
    const int tid = threadIdx.x;
    const int bid = blockIdx.x;
    const int nb = gridDim.x;                    // 512 or 1024
    const int wid = tid >> 6, lane = tid & 63;
    const int rpw = NN / (nb * 4);               // rows per wave in Phase A (1 or 2)
    const int ng = nb >> 2;                      // row groups in Phase B
    const int rpg = NN / ng;                     // rows per group (16 or 32)
    const float mean = sumC[0] * (1.0f / ((float)NN * (float)NN));
    const float nrs = -1.0f / (mean * EPSV);     // K = exp(C * nrs)
    const float invMean = 1.0f / mean;

    for (int it = 1; it <= MAX_IT; ++it) {
        // ---- Phase A: u = a / (K v + stab) ----
        if (it == 1) {
            // v0 == 0 (reference init) -> K@v0 == 0 exactly
            if (bid < 16) {
                int j = bid * 256 + tid;
                u[j] = AVAL / (0.0f + STABV);
                s[j] = 0.0f;                     // prep col accumulator
            }
        } else {
            for (int rr = 0; rr < rpw; ++rr) {
                int w = (bid * 4 + wid) * rpw + rr;   // row 0..4095, one wave each
                const unsigned short* Crow = Cb + (size_t)w * NN;
                float acc = 0.0f;
#pragma unroll
                for (int l = 0; l < 8; ++l) {
                    int c0 = l * 512 + lane * 8;
                    uint4 cw = *(const uint4*)(Crow + c0);
                    float4 v0 = *(const float4*)(v + c0);
                    float4 v1 = *(const float4*)(v + c0 + 4);
                    acc += __expf(bflo(cw.x) * nrs) * v0.x;
                    acc += __expf(bfhi(cw.x) * nrs) * v0.y;
                    acc += __expf(bflo(cw.y) * nrs) * v0.z;
                    acc += __expf(bfhi(cw.y) * nrs) * v0.w;
                    acc += __expf(bflo(cw.z) * nrs) * v1.x;
                    acc += __expf(bfhi(cw.z) * nrs) * v1.y;
                    acc += __expf(bflo(cw.w) * nrs) * v1.z;
                    acc += __expf(bfhi(cw.w) * nrs) * v1.w;
                }
#pragma unroll
                for (int off = 32; off > 0; off >>= 1) acc += __shfl_down(acc, off, 64);
                if (lane == 0) {
                    float un = AVAL / (acc + STABV);
                    if (un != u[w]) atomicOr(&flags[it & 1], 1u);
                    u[w] = un;
                }
            }
        }
        grid.sync();

        // ---- Phase B: partial col sums of K^T u (4 col-stripes x ng row-groups) ----
        {
            int jc = (bid & 3) * 1024 + tid * 4;
            int i0 = (bid >> 2) * rpg;
            float4 a4 = {0.0f, 0.0f, 0.0f, 0.0f};
            for (int r = 0; r < rpg; ++r) {
                int i = i0 + r;
                uint2 cw = *(const uint2*)(Cb + (size_t)i * NN + jc);
                float ui = u[i];
                a4.x += __expf(bflo(cw.x) * nrs) * ui;
                a4.y += __expf(bfhi(cw.x) * nrs) * ui;
                a4.z += __expf(bflo(cw.y) * nrs) * ui;
                a4.w += __expf(bfhi(cw.y) * nrs) * ui;
            }
            atomicAdd(&s[jc + 0], a4.x);
            atomicAdd(&s[jc + 1], a4.y);
            atomicAdd(&s[jc + 2], a4.z);
            atomicAdd(&s[jc + 3], a4.w);
        }
        if (bid == 0 && tid == 0)
            __hip_atomic_store(&flags[(it + 1) & 1], 0u, __ATOMIC_RELAXED, __HIP_MEMORY_SCOPE_AGENT);
        grid.sync();

        // ---- Phase C: v = b / (K^T u + stab); re-zero s for next iter ----
        if (bid < 16) {
            int j = bid * 256 + tid;
            float vn = BVAL / (s[j] + STABV);
            if (it > 1 && vn != v[j]) atomicOr(&flags[it & 1], 1u);
            v[j] = vn;
            s[j] = 0.0f;
        }
        grid.sync();

        unsigned fl = __hip_atomic_load(&flags[it & 1], __ATOMIC_RELAXED, __HIP_MEMORY_SCOPE_AGENT);
        if (it > 1 && fl == 0u) break;   // bitwise fixed point reached
    }

    // ---- cost = sum_ij u_i * K_ij * v_j * (C_ij / mean) ----
    {
        int jc = (bid & 3) * 1024 + tid * 4;
        int i0 = (bid >> 2) * rpg;
        float4 vj = *(const float4*)(v + jc);
        float4 a4 = {0.0f, 0.0f, 0.0f, 0.0f};
        for (int r = 0; r < rpg; ++r) {
            int i = i0 + r;
            uint2 cw = *(const uint2*)(Cb + (size_t)i * NN + jc);
            float ui = u[i];
            float c0 = bflo(cw.x), c1 = bfhi(cw.x), c2 = bflo(cw.y), c3 = bfhi(cw.y);
            a4.x += ui * __expf(c0 * nrs) * vj.x * (c0 * invMean);
            a4.y += ui * __expf(c1 * nrs) * vj.y * (c1 * invMean);
            a4.z += ui * __expf(c2 * nrs) * vj.z * (c2 * invMean);
            a4.w += ui * __expf(c3 * nrs) * vj.w * (c3 * invMean);
        }
        red[tid] = a4.x + a4.y + a4.z + a4.w;
        __syncthreads();
        for (int off = 128; off > 0; off >>= 1) {
            if (tid < off) red[tid] += red[tid + off];
            __syncthreads();
        }
        if (tid == 0) atomicAdd(&out[0], red[0]);
    }

    // ---- outputs: [cost, u(4096), v(4096)] ----
    if (bid < 16) {
        int j = bid * 256 + tid;
        out[1 + j] = u[j];
    } else if (bid < 32) {
        int j = (bid - 16) * 256 + tid;
        out[1 + NN + j] = v[j];
    }
}

extern "C" void kernel_launch(void* const* d_in, const int* in_sizes, int n_in,
                              void* d_out, int out_size, void* d_ws, size_t ws_size,
                              hipStream_t stream) {
    const float* x = (const float*)d_in[0];
    const float* y = (const float*)d_in[1];
    float* out = (float*)d_out;

    // ws layout
    unsigned short* Cb = (unsigned short*)d_ws;          // N*N bf16 = 32 MB
    unsigned short* xb = Cb + (size_t)NN * NN;           // N*D bf16 = 2 MB
    unsigned short* yb = xb + (size_t)NN * DD;           // N*D bf16 = 2 MB
    float* fbase = (float*)(yb + (size_t)NN * DD);
    float* x2 = fbase;                                   // N
    float* y2 = x2 + NN;                                 // N
    float* u  = y2 + NN;                                 // N
    float* v  = u + NN;                                  // N
    float* s  = v + NN;                                  // N
    float* sumC = s + NN;                                // 1
    unsigned* flags = (unsigned*)(sumC + 1);             // 2

    size_t need = (size_t)(NN * (size_t)NN + 2 * NN * DD) * 2 + (5 * NN + 8) * sizeof(float);
    if (ws_size < need) return;

    sk_init_kernel<<<1, 64, 0, stream>>>(sumC, flags, out);
    sk_conv_kernel<<<dim3(2 * NN / 4), dim3(256), 0, stream>>>(x, y, xb, yb, x2, y2);
    sk_gemm_kernel<<<dim3(NN / 128, NN / 128), dim3(256), 0, stream>>>(xb, yb, x2, y2, Cb, sumC);

    void* args[] = {(void*)&Cb, (void*)&u, (void*)&v, (void*)&s,
                    (void*)&sumC, (void*)&flags, (void*)&out};
    // 1024 blocks (4/CU) if the cooperative-launch validator accepts it;
    // otherwise fall back to 512 (2/CU) — kernel is grid-size-generic.
    hipError_t e = hipLaunchCooperativeKernel((void*)sk_coop_kernel, dim3(1024), dim3(256), args, 0, stream);
    if (e != hipSuccess) {
        (void)hipGetLastError();   // clear sticky error; no stream ops involved
        hipLaunchCooperativeKernel((void*)sk_coop_kernel, dim3(512), dim3(256), args, 0, stream);
    }
}

// Round 4
// 300.307 us; speedup vs baseline: 2.8241x; 2.8241x over previous
//
#include <hip/hip_runtime.h>
#include <math.h>

#define NN 4096
#define DD 256
#define EPSV 1e-4f
#define STABV 1e-8f
#define AVAL (1.0f / 4096.0f)
#define BVAL (1.0f / 4096.0f)
#define MAX_IT 2000

typedef __attribute__((ext_vector_type(4))) float f32x4;
typedef __attribute__((ext_vector_type(8))) short bf16x8;

__device__ inline unsigned short f2bf(float f) {   // RNE f32->bf16
    unsigned u = __float_as_uint(f);
    return (unsigned short)((u + 0x7fffu + ((u >> 16) & 1u)) >> 16);
}
__device__ inline float bflo(unsigned w) { return __uint_as_float(w << 16); }
__device__ inline float bfhi(unsigned w) { return __uint_as_float(w & 0xffff0000u); }

// ---------------- init: zero all cross-kernel state (ws is poisoned each call) ----------------
__global__ void sk_init_kernel(float* sumC, unsigned* flags, float* cost, unsigned* bar) {
    int t = threadIdx.x;
    if (t == 0) { sumC[0] = 0.0f; flags[0] = 0u; flags[1] = 0u; cost[0] = 0.0f; cost[1] = 0.0f; }
    for (int i = t; i < 384; i += 256) bar[i] = 0u;
}

// ---------------- convert f32 -> bf16 + row norms ----------------
__global__ __launch_bounds__(256) void sk_conv_kernel(const float* __restrict__ x,
                                                      const float* __restrict__ y,
                                                      unsigned short* __restrict__ xb,
                                                      unsigned short* __restrict__ yb,
                                                      float* __restrict__ x2,
                                                      float* __restrict__ y2) {
    int w = blockIdx.x * 4 + (threadIdx.x >> 6);   // row id 0..8191
    int lane = threadIdx.x & 63;
    const float* src = (w < NN) ? (x + (size_t)w * DD) : (y + (size_t)(w - NN) * DD);
    unsigned short* dst = (w < NN) ? (xb + (size_t)w * DD) : (yb + (size_t)(w - NN) * DD);
    float4 v = *(const float4*)(src + lane * 4);
    float s = v.x * v.x + v.y * v.y + v.z * v.z + v.w * v.w;
    ushort4 p;
    p.x = f2bf(v.x); p.y = f2bf(v.y); p.z = f2bf(v.z); p.w = f2bf(v.w);
    *(ushort4*)(dst + lane * 4) = p;
#pragma unroll
    for (int off = 32; off > 0; off >>= 1) s += __shfl_down(s, off, 64);
    if (lane == 0) {
        if (w < NN) x2[w] = s; else y2[w - NN] = s;
    }
}

// ---------------- MFMA GEMM: Cb = bf16( sqrt(max(x2_i + y2_j - 2 x.y, 0)) ), sum(C) ----------------
__global__ __launch_bounds__(256) void sk_gemm_kernel(const unsigned short* __restrict__ xb,
                                                      const unsigned short* __restrict__ yb,
                                                      const float* __restrict__ x2,
                                                      const float* __restrict__ y2,
                                                      unsigned short* __restrict__ Cb,
                                                      float* __restrict__ sumC) {
    __shared__ float red[256];
    const int tid = threadIdx.x;
    const int wid = tid >> 6, lane = tid & 63;
    const int wy = wid >> 1, wx = wid & 1;
    const int rb = blockIdx.y * 128 + wy * 64;
    const int cb = blockIdx.x * 128 + wx * 64;
    const int lr = lane & 15;
    const int lk = (lane >> 4) * 8;

    f32x4 acc[4][4];
    const f32x4 z4 = {0.0f, 0.0f, 0.0f, 0.0f};
#pragma unroll
    for (int a = 0; a < 4; ++a)
#pragma unroll
        for (int b = 0; b < 4; ++b) acc[a][b] = z4;

#pragma unroll
    for (int k0 = 0; k0 < DD; k0 += 32) {
        bf16x8 af[4], bfr[4];
#pragma unroll
        for (int t = 0; t < 4; ++t)
            af[t] = *(const bf16x8*)(xb + (size_t)(rb + t * 16 + lr) * DD + k0 + lk);
#pragma unroll
        for (int t = 0; t < 4; ++t)
            bfr[t] = *(const bf16x8*)(yb + (size_t)(cb + t * 16 + lr) * DD + k0 + lk);
#pragma unroll
        for (int ty = 0; ty < 4; ++ty)
#pragma unroll
            for (int tx = 0; tx < 4; ++tx)
                acc[ty][tx] = __builtin_amdgcn_mfma_f32_16x16x32_bf16(af[ty], bfr[tx], acc[ty][tx], 0, 0, 0);
    }

    float lsum = 0.0f;
#pragma unroll
    for (int ty = 0; ty < 4; ++ty) {
        float x2r[4];
#pragma unroll
        for (int r = 0; r < 4; ++r)
            x2r[r] = x2[rb + ty * 16 + (lane >> 4) * 4 + r];
#pragma unroll
        for (int tx = 0; tx < 4; ++tx) {
            int col = cb + tx * 16 + lr;
            float y2c = y2[col];
#pragma unroll
            for (int r = 0; r < 4; ++r) {
                int row = rb + ty * 16 + (lane >> 4) * 4 + r;
                float sq = x2r[r] + y2c - 2.0f * acc[ty][tx][r];
                float c = sqrtf(fmaxf(sq, 0.0f));
                lsum += c;
                Cb[(size_t)row * NN + col] = f2bf(c);
            }
        }
    }
    red[tid] = lsum;
    __syncthreads();
    for (int off = 128; off > 0; off >>= 1) {
        if (tid < off) red[tid] += red[tid + off];
        __syncthreads();
    }
    if (tid == 0) atomicAdd(sumC, red[0]);
}

// ---- hierarchical grid barrier: relaxed polling, one release/acquire fence per block ----
// bar layout (unsigned): sub-counters at [sg*32] sg=0..7, root at [256], generation at [288].
__device__ __forceinline__ void gridbar(unsigned* bar, int nb, unsigned target) {
    __syncthreads();
    if (threadIdx.x == 0) {
        const int sg = blockIdx.x & 7;
        const unsigned bps = (unsigned)(nb >> 3);
        __builtin_amdgcn_fence(__ATOMIC_RELEASE, "agent");     // flush this block's dirty lines (wbl2)
        unsigned p = __hip_atomic_fetch_add(&bar[sg * 32], 1u, __ATOMIC_RELAXED, __HIP_MEMORY_SCOPE_AGENT);
        if (p == target * bps - 1u) {                          // last in sub-group
            __builtin_amdgcn_fence(__ATOMIC_ACQUIRE, "agent");
            __builtin_amdgcn_fence(__ATOMIC_RELEASE, "agent");
            unsigned q = __hip_atomic_fetch_add(&bar[256], 1u, __ATOMIC_RELAXED, __HIP_MEMORY_SCOPE_AGENT);
            if (q == target * 8u - 1u) {                       // last overall
                __builtin_amdgcn_fence(__ATOMIC_ACQUIRE, "agent");
                __builtin_amdgcn_fence(__ATOMIC_RELEASE, "agent");
                __hip_atomic_store(&bar[288], target, __ATOMIC_RELAXED, __HIP_MEMORY_SCOPE_AGENT);
            }
        }
        while (__hip_atomic_load(&bar[288], __ATOMIC_RELAXED, __HIP_MEMORY_SCOPE_AGENT) < target)
            __builtin_amdgcn_s_sleep(2);                       // relaxed poll: NO cache ops
        __builtin_amdgcn_fence(__ATOMIC_ACQUIRE, "agent");     // single invalidate at exit
    }
    __syncthreads();
}

// ---------------- cooperative Sinkhorn: 2 barriers/iter, no reduction atomics ----------------
// Phase A: block owns NN/nb rows  -> u update (+flag).
// Phase B: block owns NN/nb cols -> full col sums -> v update (+flag) + fused cost partial.
__global__ __launch_bounds__(256, 2) void sk_coop_kernel(const unsigned short* __restrict__ Cb,
                                                         float* __restrict__ u,
                                                         float* __restrict__ v,
                                                         const float* __restrict__ sumC,
                                                         unsigned* __restrict__ flags,
                                                         float* __restrict__ cost,
                                                         unsigned* __restrict__ bar,
                                                         float* __restrict__ out) {
    __shared__ float pu[16], pv[16];
    __shared__ float wred[4][9];
    const int t = threadIdx.x;
    const int bid = blockIdx.x;
    const int nb = gridDim.x;          // 512 (or 256 fallback); multiple of 8
    const int RPB = NN / nb;           // rows/cols per block (8 or 16)
    const float mean = sumC[0] * (1.0f / ((float)NN * (float)NN));
    const float nrs = -1.0f / (mean * EPSV);   // K = exp(C * nrs)
    const float invMean = 1.0f / mean;
    unsigned bars = 0;
    int finalIt = MAX_IT;

    for (int it = 1; it <= MAX_IT; ++it) {
        // ---- Phase A: u = a / (K v + stab) ----
        if (it == 1) {
            // v0 == 0 (reference init) -> K@v0 == 0 exactly; no data needed
            if (t < RPB) {
                float u1 = AVAL / (0.0f + STABV);
                pu[t] = u1;
                u[bid * RPB + t] = u1;
            }
        } else {
            for (int rc = 0; rc < RPB; rc += 8) {
                const int r8 = t >> 5;         // 0..7: row within chunk
                const int c5 = t & 31;         // 32 threads per row
                const int i = bid * RPB + rc + r8;
                const unsigned short* Crow = Cb + (size_t)i * NN;
                float acc = 0.0f;
#pragma unroll
                for (int k = 0; k < 16; ++k) {
                    int c0 = c5 * 8 + k * 256;
                    uint4 cw = *(const uint4*)(Crow + c0);
                    float4 v0 = *(const float4*)(v + c0);
                    float4 v1 = *(const float4*)(v + c0 + 4);
                    acc += __expf(bflo(cw.x) * nrs) * v0.x;
                    acc += __expf(bfhi(cw.x) * nrs) * v0.y;
                    acc += __expf(bflo(cw.y) * nrs) * v0.z;
                    acc += __expf(bfhi(cw.y) * nrs) * v0.w;
                    acc += __expf(bflo(cw.z) * nrs) * v1.x;
                    acc += __expf(bfhi(cw.z) * nrs) * v1.y;
                    acc += __expf(bflo(cw.w) * nrs) * v1.z;
                    acc += __expf(bfhi(cw.w) * nrs) * v1.w;
                }
#pragma unroll
                for (int off = 16; off > 0; off >>= 1) acc += __shfl_down(acc, off, 32);
                if (c5 == 0) {
                    float un = AVAL / (acc + STABV);
                    if (un != pu[rc + r8])
                        __hip_atomic_fetch_or(&flags[it & 1], 1u, __ATOMIC_RELAXED, __HIP_MEMORY_SCOPE_AGENT);
                    pu[rc + r8] = un;
                    u[i] = un;
                }
            }
        }
        gridbar(bar, nb, ++bars);

        // ---- Phase B: col sums, v update, fused cost ----
        for (int cc = 0; cc < RPB; cc += 8) {
            const int j0 = bid * RPB + cc;
            float vp[8];
#pragma unroll
            for (int q = 0; q < 8; ++q) vp[q] = (it > 1) ? pv[cc + q] : 0.0f;
            float s8[8] = {0, 0, 0, 0, 0, 0, 0, 0};
            float ts = 0.0f;
#pragma unroll
            for (int k = 0; k < 16; ++k) {
                int i = t + k * 256;
                uint4 cw = *(const uint4*)(Cb + (size_t)i * NN + j0);
                float ui = u[i];
                float c, kv;
                c = bflo(cw.x); kv = __expf(c * nrs) * ui; s8[0] += kv; ts += kv * c * vp[0];
                c = bfhi(cw.x); kv = __expf(c * nrs) * ui; s8[1] += kv; ts += kv * c * vp[1];
                c = bflo(cw.y); kv = __expf(c * nrs) * ui; s8[2] += kv; ts += kv * c * vp[2];
                c = bfhi(cw.y); kv = __expf(c * nrs) * ui; s8[3] += kv; ts += kv * c * vp[3];
                c = bflo(cw.z); kv = __expf(c * nrs) * ui; s8[4] += kv; ts += kv * c * vp[4];
                c = bfhi(cw.z); kv = __expf(c * nrs) * ui; s8[5] += kv; ts += kv * c * vp[5];
                c = bflo(cw.w); kv = __expf(c * nrs) * ui; s8[6] += kv; ts += kv * c * vp[6];
                c = bfhi(cw.w); kv = __expf(c * nrs) * ui; s8[7] += kv; ts += kv * c * vp[7];
            }
#pragma unroll
            for (int off = 32; off > 0; off >>= 1) {
#pragma unroll
                for (int q = 0; q < 8; ++q) s8[q] += __shfl_down(s8[q], off, 64);
                ts += __shfl_down(ts, off, 64);
            }
            const int w = t >> 6;
            if ((t & 63) == 0) {
#pragma unroll
                for (int q = 0; q < 8; ++q) wred[w][q] = s8[q];
                wred[w][8] = ts;
            }
            __syncthreads();
            if (t < 8) {
                float s = wred[0][t] + wred[1][t] + wred[2][t] + wred[3][t];
                float vn = BVAL / (s + STABV);
                if (vn != vp[t])
                    __hip_atomic_fetch_or(&flags[it & 1], 1u, __ATOMIC_RELAXED, __HIP_MEMORY_SCOPE_AGENT);
                pv[cc + t] = vn;
                v[j0 + t] = vn;
            } else if (t == 8) {
                float tt = wred[0][8] + wred[1][8] + wred[2][8] + wred[3][8];
                atomicAdd(&cost[it & 1], tt * invMean);
            }
            __syncthreads();
        }
        if (bid == 0 && t == 0) {      // prep next-parity slots (written first in iter it+1)
            __hip_atomic_store(&flags[(it + 1) & 1], 0u, __ATOMIC_RELAXED, __HIP_MEMORY_SCOPE_AGENT);
            __hip_atomic_store(&cost[(it + 1) & 1], 0.0f, __ATOMIC_RELAXED, __HIP_MEMORY_SCOPE_AGENT);
        }
        gridbar(bar, nb, ++bars);

        finalIt = it;
        unsigned fl = __hip_atomic_load(&flags[it & 1], __ATOMIC_RELAXED, __HIP_MEMORY_SCOPE_AGENT);
        if (it > 1 && fl == 0u) break;   // bitwise fixed point: further iterations are identity
    }

    // ---- outputs: [cost, u(4096), v(4096)] ----
    if (t < RPB) {
        out[1 + bid * RPB + t] = pu[t];
        out[1 + NN + bid * RPB + t] = pv[t];
    }
    if (bid == 0 && t == 0)
        out[0] = __hip_atomic_load(&cost[finalIt & 1], __ATOMIC_RELAXED, __HIP_MEMORY_SCOPE_AGENT);
}

extern "C" void kernel_launch(void* const* d_in, const int* in_sizes, int n_in,
                              void* d_out, int out_size, void* d_ws, size_t ws_size,
                              hipStream_t stream) {
    const float* x = (const float*)d_in[0];
    const float* y = (const float*)d_in[1];
    float* out = (float*)d_out;

    // ws layout
    unsigned short* Cb = (unsigned short*)d_ws;          // N*N bf16 = 32 MB
    unsigned short* xb = Cb + (size_t)NN * NN;           // N*D bf16
    unsigned short* yb = xb + (size_t)NN * DD;           // N*D bf16
    float* fbase = (float*)(yb + (size_t)NN * DD);
    float* x2   = fbase;                                 // N
    float* y2   = x2 + NN;                               // N
    float* u    = y2 + NN;                               // N
    float* v    = u + NN;                                // N
    float* sumC = v + NN;                                // 1
    float* cost = sumC + 1;                              // 2
    unsigned* flags = (unsigned*)(cost + 2);             // 2
    unsigned* bar   = flags + 2;                         // 384 (barrier state)

    size_t need = ((size_t)NN * NN + 2 * (size_t)NN * DD) * 2 + (4 * NN + 8) * sizeof(float) + 400 * sizeof(unsigned);
    if (ws_size < need) return;

    sk_init_kernel<<<1, 256, 0, stream>>>(sumC, flags, cost, bar);
    sk_conv_kernel<<<dim3(2 * NN / 4), dim3(256), 0, stream>>>(x, y, xb, yb, x2, y2);
    sk_gemm_kernel<<<dim3(NN / 128, NN / 128), dim3(256), 0, stream>>>(xb, yb, x2, y2, Cb, sumC);

    void* args[] = {(void*)&Cb, (void*)&u, (void*)&v, (void*)&sumC,
                    (void*)&flags, (void*)&cost, (void*)&bar, (void*)&out};
    hipError_t e = hipLaunchCooperativeKernel((void*)sk_coop_kernel, dim3(512), dim3(256), args, 0, stream);
    if (e != hipSuccess) {
        (void)hipGetLastError();
        hipLaunchCooperativeKernel((void*)sk_coop_kernel, dim3(256), dim3(256), args, 0, stream);
    }
}